// Round 1
// baseline (4402.678 us; speedup 1.0000x reference)
//
// RNN_79577154060490 — round 0
// Elman RNN: h0 = p0@W_enc^T; 100× h=tanh(v@W_ih^T + h@W_hh^T); out = g@W_dec^T + b
// Strategy: bf16 MFMA (16x16x32) everywhere, fp32 accumulate + fp32 vin/tanh epilogue.
// Multi-launch (102 kernels) round 0: per-step kernel, 256 blocks x 512 thr,
// block owns 16 output columns, W-slice in LDS (fragment-swizzled, 64KB, 2 K-phases),
// h read from global (L2-resident 1MB bf16 per step).
//
// ws layout (bytes):
//   [0, 33554432)            Wb_hh  bf16 [4096*4096]
//   [33554432, 37748736)     Wb_dec bf16 [512*4096]
//   [37748736, 38797312)     H0     bf16 [128*4096]
//   [38797312, 143654912)    G      bf16 [100][128][4096]  (t-major)

#include <hip/hip_runtime.h>
#include <stdint.h>

namespace {
constexpr int kB = 128;
constexpr int kT = 100;
constexpr int kNG = 4096;
constexpr int kNP = 512;

__device__ __forceinline__ uint16_t f2bf(float f) {
  uint32_t u = __float_as_uint(f);
  u += 0x7FFFu + ((u >> 16) & 1u);  // round-to-nearest-even
  return (uint16_t)(u >> 16);
}

__device__ __forceinline__ float fast_tanh(float x) {
  float xc = fminf(fmaxf(x, -15.f), 15.f);
  float e = __expf(2.f * xc);
  return (e - 1.f) / (e + 1.f);
}
}  // namespace

typedef short bf16x8 __attribute__((ext_vector_type(8)));
typedef float f32x4 __attribute__((ext_vector_type(4)));

// ---- fp32 -> bf16 bulk convert (vectorized) ----
__global__ void cvt4_kernel(const float4* __restrict__ src, ushort4* __restrict__ dst, int n4) {
  int i = blockIdx.x * blockDim.x + threadIdx.x;
  const int stride = gridDim.x * blockDim.x;
  for (; i < n4; i += stride) {
    float4 f = src[i];
    ushort4 o;
    o.x = f2bf(f.x);
    o.y = f2bf(f.y);
    o.z = f2bf(f.z);
    o.w = f2bf(f.w);
    dst[i] = o;
  }
}

// ---- encoder: H0[b,g] = sum_k p0[b,k] * Wenc[g,k], bf16 out ----
// 256 blocks x 512 thr; block owns 16 g-columns; K=512 (16 k-tiles).
__global__ __launch_bounds__(512, 2) void enc_kernel(const float* __restrict__ p0,
                                                     const float* __restrict__ Wenc,
                                                     uint16_t* __restrict__ H0) {
  __shared__ alignas(16) uint16_t Wlds[16 * 64 * 8];  // fragment-swizzled [kt][lane][8]
  const int tid = threadIdx.x;
  const int g0 = blockIdx.x * 16;
  for (int f = tid; f < 16 * 64; f += 512) {
    const int kt = f >> 6, fl = f & 63;
    const int g = g0 + (fl & 15);
    const int k = kt * 32 + ((fl >> 4) << 3);
    const float* s = Wenc + (size_t)g * kNP + k;
    uint16_t* d = Wlds + f * 8;
#pragma unroll
    for (int j = 0; j < 8; j++) d[j] = f2bf(s[j]);
  }
  __syncthreads();
  const int wave = tid >> 6;
  const int lane = tid & 63;
  const int mrow = wave * 16 + (lane & 15);
  const float* arow = p0 + (size_t)mrow * kNP + ((lane >> 4) << 3);
  f32x4 acc = {0.f, 0.f, 0.f, 0.f};
#pragma unroll
  for (int kt = 0; kt < 16; kt++) {
    const float* ap = arow + kt * 32;
    bf16x8 a;
#pragma unroll
    for (int j = 0; j < 8; j++) a[j] = (short)f2bf(ap[j]);
    bf16x8 b = *(const bf16x8*)(Wlds + (kt * 64 + lane) * 8);
    acc = __builtin_amdgcn_mfma_f32_16x16x32_bf16(a, b, acc, 0, 0, 0);
  }
  const int gcol = g0 + (lane & 15);
  const int rbase = wave * 16 + ((lane >> 4) << 2);
#pragma unroll
  for (int r = 0; r < 4; r++) {
    H0[(size_t)(rbase + r) * kNG + gcol] = f2bf(acc[r]);
  }
}

// ---- one RNN step: Hout[b,g] = tanh(v[b,t,:].Wih[g,:] + sum_k Hin[b,k]*Wb[g,k]) ----
// 256 blocks x 512 thr (8 waves, one 16-row M-tile each); K=4096 in 2 phases of 64 k-tiles.
__global__ __launch_bounds__(512, 2) void step_kernel(const uint16_t* __restrict__ Hin,
                                                      uint16_t* __restrict__ Hout,
                                                      const uint16_t* __restrict__ Wb,
                                                      const float* __restrict__ v,
                                                      const float* __restrict__ Wih,
                                                      int t) {
  __shared__ alignas(16) uint16_t Wlds[64 * 64 * 8];  // 64 KB, swizzled [ktl][lane][8]
  const int tid = threadIdx.x;
  const int g0 = blockIdx.x * 16;
  const int wave = tid >> 6;
  const int lane = tid & 63;
  const int mrow = wave * 16 + (lane & 15);
  const uint16_t* arow = Hin + (size_t)mrow * kNG + ((lane >> 4) << 3);
  f32x4 acc = {0.f, 0.f, 0.f, 0.f};
  for (int phase = 0; phase < 2; phase++) {
    for (int f = tid; f < 64 * 64; f += 512) {
      const int ktl = f >> 6, fl = f & 63;
      const int g = g0 + (fl & 15);
      const int k = (phase * 64 + ktl) * 32 + ((fl >> 4) << 3);
      *(uint4*)(Wlds + f * 8) = *(const uint4*)(Wb + (size_t)g * kNG + k);
    }
    __syncthreads();
#pragma unroll 4
    for (int ktl = 0; ktl < 64; ktl++) {
      bf16x8 a = *(const bf16x8*)(arow + (phase * 64 + ktl) * 32);
      bf16x8 b = *(const bf16x8*)(Wlds + (ktl * 64 + lane) * 8);
      acc = __builtin_amdgcn_mfma_f32_16x16x32_bf16(a, b, acc, 0, 0, 0);
    }
    __syncthreads();
  }
  const int gcol = g0 + (lane & 15);
  const float wih0 = Wih[gcol * 2 + 0];
  const float wih1 = Wih[gcol * 2 + 1];
  const int rbase = wave * 16 + ((lane >> 4) << 2);
#pragma unroll
  for (int r = 0; r < 4; r++) {
    const int b = rbase + r;
    const float2 vv = *(const float2*)(v + ((size_t)b * kT + t) * 2);
    float pre = acc[r] + vv.x * wih0 + vv.y * wih1;
    Hout[(size_t)b * kNG + gcol] = f2bf(fast_tanh(pre));
  }
}

// ---- decoder: out[b,t,p] = sum_g G[t,b,g]*Wd[p,g] + bd[p] ----
// M = 12800 rows (t*128+b, row-major in G), N = 512, K = 4096.
// 1600 blocks x 1024 thr: block = 256 M-rows x 16 p-cols; 2 K-phases of 64 k-tiles.
__global__ __launch_bounds__(1024, 4) void dec_kernel(const uint16_t* __restrict__ G,
                                                      const uint16_t* __restrict__ Wd,
                                                      const float* __restrict__ bd,
                                                      float* __restrict__ out) {
  __shared__ alignas(16) uint16_t Wlds[64 * 64 * 8];  // 64 KB
  const int tid = threadIdx.x;
  const int bid = blockIdx.x;
  const int nt = bid & 31;   // p-tile, fastest-varying -> XCD-pinned W slice in L2
  const int mb = bid >> 5;   // 50 M-blocks of 256 rows
  const int p0c = nt * 16;
  const int wave = tid >> 6;  // 0..15
  const int lane = tid & 63;
  const int mrow = mb * 256 + wave * 16 + (lane & 15);
  const uint16_t* arow = G + (size_t)mrow * kNG + ((lane >> 4) << 3);
  f32x4 acc = {0.f, 0.f, 0.f, 0.f};
  for (int phase = 0; phase < 2; phase++) {
    for (int f = tid; f < 64 * 64; f += 1024) {
      const int ktl = f >> 6, fl = f & 63;
      const int p = p0c + (fl & 15);
      const int k = (phase * 64 + ktl) * 32 + ((fl >> 4) << 3);
      *(uint4*)(Wlds + f * 8) = *(const uint4*)(Wd + (size_t)p * kNG + k);
    }
    __syncthreads();
#pragma unroll 4
    for (int ktl = 0; ktl < 64; ktl++) {
      bf16x8 a = *(const bf16x8*)(arow + (phase * 64 + ktl) * 32);
      bf16x8 b = *(const bf16x8*)(Wlds + (ktl * 64 + lane) * 8);
      acc = __builtin_amdgcn_mfma_f32_16x16x32_bf16(a, b, acc, 0, 0, 0);
    }
    __syncthreads();
  }
  const int pcol = p0c + (lane & 15);
  const float bias = bd[pcol];
  const int rbase = mb * 256 + wave * 16 + ((lane >> 4) << 2);
#pragma unroll
  for (int r = 0; r < 4; r++) {
    const int m = rbase + r;
    const int tt = m >> 7;   // G is [t][b][g]
    const int bb = m & 127;
    out[((size_t)bb * kT + tt) * kNP + pcol] = acc[r] + bias;
  }
}

extern "C" void kernel_launch(void* const* d_in, const int* in_sizes, int n_in,
                              void* d_out, int out_size, void* d_ws, size_t ws_size,
                              hipStream_t stream) {
  const float* v    = (const float*)d_in[0];   // [128,100,2]
  const float* p0   = (const float*)d_in[1];   // [128,512]
  const float* Wenc = (const float*)d_in[2];   // [4096,512]
  const float* Wih  = (const float*)d_in[3];   // [4096,2]
  const float* Whh  = (const float*)d_in[4];   // [4096,4096]
  const float* Wdec = (const float*)d_in[5];   // [512,4096]
  const float* bdec = (const float*)d_in[6];   // [512]
  float* out = (float*)d_out;

  uint8_t* ws = (uint8_t*)d_ws;
  uint16_t* Wb_hh  = (uint16_t*)(ws);
  uint16_t* Wb_dec = (uint16_t*)(ws + 33554432);
  uint16_t* H0     = (uint16_t*)(ws + 37748736);
  uint16_t* G      = (uint16_t*)(ws + 38797312);

  cvt4_kernel<<<4096, 256, 0, stream>>>((const float4*)Whh, (ushort4*)Wb_hh, kNG * kNG / 4);
  cvt4_kernel<<<512, 256, 0, stream>>>((const float4*)Wdec, (ushort4*)Wb_dec, kNP * kNG / 4);
  enc_kernel<<<256, 512, 0, stream>>>(p0, Wenc, H0);

  for (int t = 0; t < kT; t++) {
    const uint16_t* Hin = (t == 0) ? H0 : (G + (size_t)(t - 1) * kB * kNG);
    uint16_t* Hout = G + (size_t)t * kB * kNG;
    step_kernel<<<256, 512, 0, stream>>>(Hin, Hout, Wb_hh, v, Wih, t);
  }

  dec_kernel<<<1600, 1024, 0, stream>>>(G, Wb_dec, bdec, out);
}

// Round 2
// 1966.254 us; speedup vs baseline: 2.2391x; 2.2391x over previous
//
// RNN_79577154060490 — round 1
// h0 = p0@W_enc^T; 100x h=tanh(v@W_ih^T + h@W_hh^T); out = g@W_dec^T + b
// All GEMMs: bf16 MFMA 16x16x32, fp32 accum. All weight/activation tensors stored
// in pre-swizzled MFMA fragment-image order so LDS staging is a LINEAR copy done
// with __builtin_amdgcn_global_load_lds (16B/lane, 1KB/wave-instr).
//
// Fragment images (per 32KB chunk = 128 rows/cols x 128 k):
//   A-image: [chunk][mt(8)][ktl(4)][lane(64)][8]   lane = (k>>3 &3)*16 + (b&15)
//   B-image: [chunk][nt(8)][ktl(4)][lane(64)][8]   lane = (k>>3 &3)*16 + (c&15)
//
// Per step: stepmm (256 blk = 32 gt x 8 ks; A 128KB + W 128KB via LDS; Part fp32)
//           steptanh (sum 8 partials + vin + tanh -> G_swz[t])
// Decoder: m97-style 128x128 tile, K=4096 in 32 chunks, same staging.
//
// ws layout (bytes):
//   [0,         33554432)   WhS  bf16 [gt32][chunk32][nt8][ktl4][64][8]
//   [33554432,  37748736)   WdS  bf16 [pt4][chunk32][nt8][ktl4][64][8]
//   [37748736,  38797312)   H0S  bf16 A-image (1MB)
//   [38797312, 143654912)   Gsw  bf16 [t100] A-images (100MB)
//   [143654912,160432128)   Part fp32 [ks8][128][4096] (16MB)

#include <hip/hip_runtime.h>
#include <stdint.h>

namespace {
constexpr int kT = 100;
constexpr int kNG = 4096;
constexpr int kNP = 512;

__device__ __forceinline__ uint16_t f2bf(float f) {
  uint32_t u = __float_as_uint(f);
  u += 0x7FFFu + ((u >> 16) & 1u);
  return (uint16_t)(u >> 16);
}

__device__ __forceinline__ float fast_tanh(float x) {
  float xc = fminf(fmaxf(x, -15.f), 15.f);
  float e = __expf(2.f * xc);
  return (e - 1.f) / (e + 1.f);
}

__device__ __forceinline__ void gl2lds16(const void* g, void* l) {
  __builtin_amdgcn_global_load_lds((const __attribute__((address_space(1))) unsigned int*)g,
                                   (__attribute__((address_space(3))) unsigned int*)l, 16, 0, 0);
}

// fragment-image element offsets (within one tensor)
__device__ __forceinline__ size_t a_img_off(int b, int g) {  // g = k index
  return ((size_t)(((g >> 7) * 8 + (b >> 4)) * 4 + ((g >> 5) & 3)) * 64 +
          ((g >> 3) & 3) * 16 + (b & 15)) * 8 + (g & 7);
}
}  // namespace

typedef short bf16x8 __attribute__((ext_vector_type(8)));
typedef float f32x4 __attribute__((ext_vector_type(4)));

// ---- swizzle-convert W_hh fp32 [4096][4096] -> WhS B-image bf16 ----
__global__ __launch_bounds__(512) void cvt_whh_kernel(const float* __restrict__ W,
                                                      uint16_t* __restrict__ WhS) {
  const int idx = blockIdx.x * 512 + threadIdx.x;  // 2M threads
  const int g = idx >> 9;
  const int k0 = (idx & 511) << 3;
  const float4 x = *(const float4*)(W + (size_t)g * kNG + k0);
  const float4 y = *(const float4*)(W + (size_t)g * kNG + k0 + 4);
  uint4 u;
  u.x = (uint32_t)f2bf(x.x) | ((uint32_t)f2bf(x.y) << 16);
  u.y = (uint32_t)f2bf(x.z) | ((uint32_t)f2bf(x.w) << 16);
  u.z = (uint32_t)f2bf(y.x) | ((uint32_t)f2bf(y.y) << 16);
  u.w = (uint32_t)f2bf(y.z) | ((uint32_t)f2bf(y.w) << 16);
  const int gt = g >> 7, c = g & 127;
  const int nt = c >> 4, col = c & 15;
  const int chunk = k0 >> 7, ktl = (k0 >> 5) & 3, half = (k0 >> 3) & 3;
  const size_t off = ((size_t)(((gt * 32 + chunk) * 8 + nt) * 4 + ktl) * 64 + half * 16 + col) * 8;
  *(uint4*)(WhS + off) = u;
}

// ---- swizzle-convert W_dec fp32 [512][4096] -> WdS B-image bf16 ----
__global__ __launch_bounds__(512) void cvt_wdec_kernel(const float* __restrict__ W,
                                                       uint16_t* __restrict__ WdS) {
  const int idx = blockIdx.x * 512 + threadIdx.x;  // 256K threads
  const int p = idx >> 9;
  const int k0 = (idx & 511) << 3;
  const float4 x = *(const float4*)(W + (size_t)p * kNG + k0);
  const float4 y = *(const float4*)(W + (size_t)p * kNG + k0 + 4);
  uint4 u;
  u.x = (uint32_t)f2bf(x.x) | ((uint32_t)f2bf(x.y) << 16);
  u.y = (uint32_t)f2bf(x.z) | ((uint32_t)f2bf(x.w) << 16);
  u.z = (uint32_t)f2bf(y.x) | ((uint32_t)f2bf(y.y) << 16);
  u.w = (uint32_t)f2bf(y.z) | ((uint32_t)f2bf(y.w) << 16);
  const int pt = p >> 7, c = p & 127;
  const int nt = c >> 4, col = c & 15;
  const int chunk = k0 >> 7, ktl = (k0 >> 5) & 3, half = (k0 >> 3) & 3;
  const size_t off = ((size_t)(((pt * 32 + chunk) * 8 + nt) * 4 + ktl) * 64 + half * 16 + col) * 8;
  *(uint4*)(WdS + off) = u;
}

// ---- encoder: H0S = A-image of p0 @ Wenc^T (bf16) ----
__global__ __launch_bounds__(512, 2) void enc_kernel(const float* __restrict__ p0,
                                                     const float* __restrict__ Wenc,
                                                     uint16_t* __restrict__ H0S) {
  __shared__ alignas(16) uint16_t Wlds[16 * 64 * 8];
  const int tid = threadIdx.x;
  const int g0 = blockIdx.x * 16;
  for (int f = tid; f < 16 * 64; f += 512) {
    const int kt = f >> 6, fl = f & 63;
    const int g = g0 + (fl & 15);
    const int k = kt * 32 + ((fl >> 4) << 3);
    const float* s = Wenc + (size_t)g * kNP + k;
    uint16_t* d = Wlds + f * 8;
#pragma unroll
    for (int j = 0; j < 8; j++) d[j] = f2bf(s[j]);
  }
  __syncthreads();
  const int wave = tid >> 6;
  const int lane = tid & 63;
  const int mrow = wave * 16 + (lane & 15);
  const float* arow = p0 + (size_t)mrow * kNP + ((lane >> 4) << 3);
  f32x4 acc = {0.f, 0.f, 0.f, 0.f};
#pragma unroll
  for (int kt = 0; kt < 16; kt++) {
    const float* ap = arow + kt * 32;
    bf16x8 a;
#pragma unroll
    for (int j = 0; j < 8; j++) a[j] = (short)f2bf(ap[j]);
    bf16x8 b = *(const bf16x8*)(Wlds + (kt * 64 + lane) * 8);
    acc = __builtin_amdgcn_mfma_f32_16x16x32_bf16(a, b, acc, 0, 0, 0);
  }
  const int gcol = g0 + (lane & 15);
  const int rbase = wave * 16 + ((lane >> 4) << 2);
#pragma unroll
  for (int r = 0; r < 4; r++) {
    H0S[a_img_off(rbase + r, gcol)] = f2bf(acc[r]);
  }
}

// ---- stepmm: partial GEMM. block = (gt, ks); C_part[128 b x 128 g] over 512 k ----
__global__ __launch_bounds__(512, 4) void stepmm_kernel(const uint16_t* __restrict__ Asrc,
                                                        const uint16_t* __restrict__ WhS,
                                                        float* __restrict__ Part) {
  __shared__ alignas(16) uint16_t lds[32768];  // 64KB: [0,16384)=A, [16384,32768)=B
  const int tid = threadIdx.x;
  const int wave = tid >> 6, lane = tid & 63;
  const int gt = blockIdx.x >> 3, ks = blockIdx.x & 7;
  const int mg = wave >> 1, ng = wave & 1;
  const uint16_t* Wbase = WhS + ((size_t)gt << 19);
  f32x4 acc[2][4];
#pragma unroll
  for (int i = 0; i < 2; i++)
#pragma unroll
    for (int j = 0; j < 4; j++) acc[i][j] = (f32x4){0.f, 0.f, 0.f, 0.f};

  for (int kc = 0; kc < 4; kc++) {
    const int chunk = ks * 4 + kc;
    const uint16_t* Ac = Asrc + ((size_t)chunk << 14);
    const uint16_t* Bc = Wbase + ((size_t)chunk << 14);
#pragma unroll
    for (int i = 0; i < 8; i++) {
      const int j = wave * 8 + i;  // wave-uniform
      const uint16_t* s = (j < 32) ? (Ac + (j << 9)) : (Bc + ((j - 32) << 9));
      gl2lds16(s + (lane << 3), (void*)(lds + (j << 9)));
    }
    __syncthreads();
    const uint16_t* lA = lds;
    const uint16_t* lB = lds + 16384;
#pragma unroll
    for (int ktl = 0; ktl < 4; ktl++) {
      bf16x8 a0 = *(const bf16x8*)(lA + ((((mg * 2 + 0) * 4 + ktl) * 64 + lane) << 3));
      bf16x8 a1 = *(const bf16x8*)(lA + ((((mg * 2 + 1) * 4 + ktl) * 64 + lane) << 3));
#pragma unroll
      for (int nt = 0; nt < 4; nt++) {
        bf16x8 b = *(const bf16x8*)(lB + ((((ng * 4 + nt) * 4 + ktl) * 64 + lane) << 3));
        acc[0][nt] = __builtin_amdgcn_mfma_f32_16x16x32_bf16(a0, b, acc[0][nt], 0, 0, 0);
        acc[1][nt] = __builtin_amdgcn_mfma_f32_16x16x32_bf16(a1, b, acc[1][nt], 0, 0, 0);
      }
    }
    __syncthreads();
  }
  const int g0 = (gt << 7) + (ng << 6);
  const int rb = (mg << 5) + ((lane >> 4) << 2);
#pragma unroll
  for (int mi = 0; mi < 2; mi++)
#pragma unroll
    for (int nt = 0; nt < 4; nt++)
#pragma unroll
      for (int r = 0; r < 4; r++) {
        const int b = rb + (mi << 4) + r;
        const int g = g0 + (nt << 4) + (lane & 15);
        Part[(((size_t)(ks * 128 + b)) << 12) + g] = acc[mi][nt][r];
      }
}

// ---- steptanh: H'(t) = tanh(sum_ks Part + vin) -> Gsw[t] (A-image bf16) ----
__global__ __launch_bounds__(256) void steptanh_kernel(const float* __restrict__ Part,
                                                       const float* __restrict__ v,
                                                       const float* __restrict__ Wih,
                                                       uint16_t* __restrict__ Gt, int t) {
  const int tg = blockIdx.x * 256 + threadIdx.x;  // 65536
  const int b = tg >> 9;
  const int g0 = (tg & 511) << 3;
  float s[8];
#pragma unroll
  for (int j = 0; j < 8; j++) s[j] = 0.f;
#pragma unroll
  for (int ks = 0; ks < 8; ks++) {
    const float4* p = (const float4*)(Part + (((size_t)(ks * 128 + b)) << 12) + g0);
    const float4 x = p[0], y = p[1];
    s[0] += x.x; s[1] += x.y; s[2] += x.z; s[3] += x.w;
    s[4] += y.x; s[5] += y.y; s[6] += y.z; s[7] += y.w;
  }
  const float v0 = v[(b * kT + t) * 2 + 0];
  const float v1 = v[(b * kT + t) * 2 + 1];
  uint16_t h[8];
#pragma unroll
  for (int j = 0; j < 8; j++) {
    const int g = g0 + j;
    const float pre = s[j] + v0 * Wih[g * 2 + 0] + v1 * Wih[g * 2 + 1];
    h[j] = f2bf(fast_tanh(pre));
  }
  uint4 u;
  u.x = (uint32_t)h[0] | ((uint32_t)h[1] << 16);
  u.y = (uint32_t)h[2] | ((uint32_t)h[3] << 16);
  u.z = (uint32_t)h[4] | ((uint32_t)h[5] << 16);
  u.w = (uint32_t)h[6] | ((uint32_t)h[7] << 16);
  const size_t off = ((size_t)(((g0 >> 7) * 8 + (b >> 4)) * 4 + ((g0 >> 5) & 3)) * 64 +
                      ((g0 >> 3) & 3) * 16 + (b & 15)) * 8;
  *(uint4*)(Gt + off) = u;
}

// ---- decoder: out[b,t,p] = Gsw[t] @ WdS[pt] + bias. block=(t, pt), 32 k-chunks ----
__global__ __launch_bounds__(512, 4) void dec_kernel(const uint16_t* __restrict__ Gsw,
                                                     const uint16_t* __restrict__ WdS,
                                                     const float* __restrict__ bd,
                                                     float* __restrict__ out) {
  __shared__ alignas(16) uint16_t lds[32768];
  const int tid = threadIdx.x;
  const int wave = tid >> 6, lane = tid & 63;
  const int t = blockIdx.x >> 2, pt = blockIdx.x & 3;
  const int mg = wave >> 1, ng = wave & 1;
  const uint16_t* Abase = Gsw + (size_t)t * 524288;
  const uint16_t* Bbase = WdS + (size_t)pt * 524288;
  f32x4 acc[2][4];
#pragma unroll
  for (int i = 0; i < 2; i++)
#pragma unroll
    for (int j = 0; j < 4; j++) acc[i][j] = (f32x4){0.f, 0.f, 0.f, 0.f};

  for (int chunk = 0; chunk < 32; chunk++) {
    const uint16_t* Ac = Abase + ((size_t)chunk << 14);
    const uint16_t* Bc = Bbase + ((size_t)chunk << 14);
#pragma unroll
    for (int i = 0; i < 8; i++) {
      const int j = wave * 8 + i;
      const uint16_t* s = (j < 32) ? (Ac + (j << 9)) : (Bc + ((j - 32) << 9));
      gl2lds16(s + (lane << 3), (void*)(lds + (j << 9)));
    }
    __syncthreads();
    const uint16_t* lA = lds;
    const uint16_t* lB = lds + 16384;
#pragma unroll
    for (int ktl = 0; ktl < 4; ktl++) {
      bf16x8 a0 = *(const bf16x8*)(lA + ((((mg * 2 + 0) * 4 + ktl) * 64 + lane) << 3));
      bf16x8 a1 = *(const bf16x8*)(lA + ((((mg * 2 + 1) * 4 + ktl) * 64 + lane) << 3));
#pragma unroll
      for (int nt = 0; nt < 4; nt++) {
        bf16x8 b = *(const bf16x8*)(lB + ((((ng * 4 + nt) * 4 + ktl) * 64 + lane) << 3));
        acc[0][nt] = __builtin_amdgcn_mfma_f32_16x16x32_bf16(a0, b, acc[0][nt], 0, 0, 0);
        acc[1][nt] = __builtin_amdgcn_mfma_f32_16x16x32_bf16(a1, b, acc[1][nt], 0, 0, 0);
      }
    }
    __syncthreads();
  }
  const int p0c = (pt << 7) + (ng << 6);
  const int rb = (mg << 5) + ((lane >> 4) << 2);
#pragma unroll
  for (int mi = 0; mi < 2; mi++)
#pragma unroll
    for (int nt = 0; nt < 4; nt++) {
      const int p = p0c + (nt << 4) + (lane & 15);
      const float bias = bd[p];
#pragma unroll
      for (int r = 0; r < 4; r++) {
        const int b = rb + (mi << 4) + r;
        out[((size_t)b * kT + t) * kNP + p] = acc[mi][nt][r] + bias;
      }
    }
}

extern "C" void kernel_launch(void* const* d_in, const int* in_sizes, int n_in,
                              void* d_out, int out_size, void* d_ws, size_t ws_size,
                              hipStream_t stream) {
  const float* v    = (const float*)d_in[0];
  const float* p0   = (const float*)d_in[1];
  const float* Wenc = (const float*)d_in[2];
  const float* Wih  = (const float*)d_in[3];
  const float* Whh  = (const float*)d_in[4];
  const float* Wdec = (const float*)d_in[5];
  const float* bdec = (const float*)d_in[6];
  float* out = (float*)d_out;

  uint8_t* ws = (uint8_t*)d_ws;
  uint16_t* WhS = (uint16_t*)(ws);
  uint16_t* WdS = (uint16_t*)(ws + 33554432);
  uint16_t* H0S = (uint16_t*)(ws + 37748736);
  uint16_t* Gsw = (uint16_t*)(ws + 38797312);
  float*    Part = (float*)(ws + 143654912);

  cvt_whh_kernel<<<4096, 512, 0, stream>>>(Whh, WhS);
  cvt_wdec_kernel<<<512, 512, 0, stream>>>(Wdec, WdS);
  enc_kernel<<<256, 512, 0, stream>>>(p0, Wenc, H0S);

  for (int t = 0; t < kT; t++) {
    const uint16_t* Asrc = (t == 0) ? H0S : (Gsw + (size_t)(t - 1) * 524288);
    stepmm_kernel<<<256, 512, 0, stream>>>(Asrc, WhS, Part);
    steptanh_kernel<<<256, 256, 0, stream>>>(Part, v, Wih, Gsw + (size_t)t * 524288, t);
  }

  dec_kernel<<<400, 512, 0, stream>>>(Gsw, WdS, bdec, out);
}